// Round 12
// baseline (111.160 us; speedup 1.0000x reference)
//
#include <hip/hip_runtime.h>

#define N_Q  100000
#define N_M  5000
#define G    128
#define NC   (G * G)                    // 16384 cells
#define RMAX 6
// Fixed box: correctness does NOT depend on data being inside (outliers clamp
// to edge cells; ring bound stays valid; out-of-box queries -> brute).
#define MNX  (-6.0f)
#define MNY  (-6.0f)
#define CWC  0.09375f                   // 12/128, exact binary
#define IVC  (1.0f / CWC)               // compile-time fold, same in all kernels

#define MC_OFF_B   64                         // maze cell cursors  [NC]
#define QC_OFF_B   (MC_OFF_B + NC * 4)        // 65600: query cursors [NC]
#define SORT_OFF_B (QC_OFF_B + NC * 4)        // 131136: sorted pts {x,y,ts,idx}
#define SQ_OFF_B   (SORT_OFF_B + N_M * 16)    // 211136: sorted query ids
#define OVF_OFF_B  (SQ_OFF_B + N_Q * 4)       // 611136: overflow list
#define OVF_CAP    32768
#define WS_NEED    (OVF_OFF_B + OVF_CAP * 4)  // 742208
#define ZERO_INTS  ((MC_OFF_B + 2 * NC * 4) / 4)   // ovfcnt + mcur + qcur

__device__ __forceinline__ int cell_of(float x, float y) {
    int cx = (int)((x - MNX) * IVC);
    int cy = (int)((y - MNY) * IVC);
    cx = min(G - 1, max(0, cx));
    cy = min(G - 1, max(0, cy));
    return cy * G + cx;
}

// ---- zero counters (no hipMemsetAsync API risk inside capture) -------------
__global__ void k_zero(int* ws) {
    const int i = blockIdx.x * 256 + threadIdx.x;
    for (int j = i; j < ZERO_INTS; j += gridDim.x * 256) ws[j] = 0;
}

// ---- dual histogram: maze points and queries ------------------------------
__global__ __launch_bounds__(256) void k_hist(
    const float* __restrict__ q, const float* __restrict__ maze,
    float* __restrict__ ws)
{
    const int i = blockIdx.x * 256 + threadIdx.x;
    int* mc = (int*)((char*)ws + MC_OFF_B);
    int* qc = (int*)((char*)ws + QC_OFF_B);
    if (i < N_M) {
        const float2 p = ((const float2*)maze)[i];
        atomicAdd(&mc[cell_of(p.x, p.y)], 1);
    }
    if (i < N_Q) {
        const float2 p = ((const float2*)q)[i];
        atomicAdd(&qc[cell_of(p.x, p.y)], 1);
    }
}

// ---- exclusive scan of both 16384-cell arrays (one 1024-thread block) -----
__global__ __launch_bounds__(1024) void k_scan(float* __restrict__ ws) {
    __shared__ int wsum[16];
    const int t = threadIdx.x, lane = t & 63, wv = t >> 6;
    int* arr0 = (int*)((char*)ws + MC_OFF_B);
    int* arr1 = (int*)((char*)ws + QC_OFF_B);
    for (int a = 0; a < 2; ++a) {
        int* arr = a ? arr1 : arr0;
        const int base = t * 16;                 // 1024*16 = 16384 exact
        int loc[16], sum = 0;
        #pragma unroll
        for (int j = 0; j < 16; ++j) { loc[j] = sum; sum += arr[base + j]; }
        int incl = sum;
        #pragma unroll
        for (int s = 1; s < 64; s <<= 1) {
            const int o = __shfl_up(incl, s);
            if (lane >= s) incl += o;
        }
        if (lane == 63) wsum[wv] = incl;
        __syncthreads();
        int wbase = 0;
        #pragma unroll
        for (int w = 0; w < 16; ++w) wbase += (w < wv) ? wsum[w] : 0;
        const int excl = wbase + incl - sum;
        #pragma unroll
        for (int j = 0; j < 16; ++j) arr[base + j] = excl + loc[j];
        __syncthreads();                         // protect wsum reuse
    }
}

// ---- dual scatter: maze -> sorted records, queries -> sorted id list ------
// After the atomicAdds the cursor arrays hold INCLUSIVE ends:
// span(c) = [c ? cur[c-1] : 0, cur[c]).  Scatter order within a cell is
// nondeterministic; queries use order-free (d2,idx) lex-min -> deterministic.
__global__ __launch_bounds__(256) void k_scat(
    const float* __restrict__ q, const float* __restrict__ maze,
    const float* __restrict__ ts, float* __restrict__ ws)
{
    const int i = blockIdx.x * 256 + threadIdx.x;
    int* mc = (int*)((char*)ws + MC_OFF_B);
    int* qc = (int*)((char*)ws + QC_OFF_B);
    if (i < N_M) {
        const float2 p = ((const float2*)maze)[i];
        const int pos = atomicAdd(&mc[cell_of(p.x, p.y)], 1);
        float4 e; e.x = p.x; e.y = p.y; e.z = ts[i]; e.w = __int_as_float(i);
        ((float4*)((char*)ws + SORT_OFF_B))[pos] = e;
    }
    if (i < N_Q) {
        const float2 p = ((const float2*)q)[i];
        const int pos = atomicAdd(&qc[cell_of(p.x, p.y)], 1);
        ((int*)((char*)ws + SQ_OFF_B))[pos] = i;
    }
}

// ---- sorted-query ring search ----------------------------------------------
// Lanes hold cell-sorted queries -> wave-coherent gathers (L1 broadcast) and
// uniform ring depth. Exact numpy IEEE sequence (sub,mul,mul,add; no FMA);
// (d2, orig_idx) lex-min is visit-order-free -> bit-exact vs argmin.
__global__ __launch_bounds__(256) void grid_query(
    const float* __restrict__ q, float* __restrict__ ws,
    float* __restrict__ out)
{
    const int ii = blockIdx.x * 256 + threadIdx.x;
    const int si = ii < N_Q ? ii : N_Q - 1;          // tail dup: idempotent
    const int qi = ((const int*)((const char*)ws + SQ_OFF_B))[si];

    const int*    mc     = (const int*)((const char*)ws + MC_OFF_B);
    const float4* sorted = (const float4*)((const char*)ws + SORT_OFF_B);

    const float2 Q = ((const float2*)q)[qi];
    const float qx = Q.x, qy = Q.y;
    int cx = (int)((qx - MNX) * IVC); cx = min(G - 1, max(0, cx));
    int cy = (int)((qy - MNY) * IVC); cy = min(G - 1, max(0, cy));

    float bd2 = 3.4e38f;
    int bidx = 0x7fffffff;

    auto cstart = [&](int c) -> int { return c ? mc[c - 1] : 0; };
    auto cand = [&](const float4 c) {
        const float dx = __fsub_rn(qx, c.x);
        const float dy = __fsub_rn(qy, c.y);
        const float d2 = __fadd_rn(__fmul_rn(dx, dx), __fmul_rn(dy, dy));
        const int idx = __float_as_int(c.w);
        if (d2 < bd2 || (d2 == bd2 && idx < bidx)) { bd2 = d2; bidx = idx; }
    };
    auto scan8 = [&](int s, int e) {                 // 8 loads in flight; tail
        for (int p = s; p < e; p += 8) {             // dups idempotent
            const float4 c0 = sorted[p];
            const float4 c1 = sorted[p + 1 < e ? p + 1 : p];
            const float4 c2 = sorted[p + 2 < e ? p + 2 : p];
            const float4 c3 = sorted[p + 3 < e ? p + 3 : p];
            const float4 c4 = sorted[p + 4 < e ? p + 4 : p];
            const float4 c5 = sorted[p + 5 < e ? p + 5 : p];
            const float4 c6 = sorted[p + 6 < e ? p + 6 : p];
            const float4 c7 = sorted[p + 7 < e ? p + 7 : p];
            cand(c0); cand(c1); cand(c2); cand(c3);
            cand(c4); cand(c5); cand(c6); cand(c7);
        }
    };
    // unscanned points lie outside world-rect of cells [cx±r]x[cy±r];
    // >1-ulp conservative slack on the fp edge computation.
    auto bound_ok = [&](int r) -> bool {
        const float Xlo = MNX + (float)(cx - r) * CWC;
        const float Xhi = MNX + (float)(cx + r + 1) * CWC;
        const float Ylo = MNY + (float)(cy - r) * CWC;
        const float Yhi = MNY + (float)(cy + r + 1) * CWC;
        float lb = fminf(fminf(qx - Xlo, Xhi - qx), fminf(qy - Ylo, Yhi - qy));
        lb = lb * 0.9999f - 1e-6f;
        return (lb > 0.0f) && (lb * lb > bd2);
    };

    // 3x3 box: one contiguous span per row (border rows may duplicate ->
    // idempotent under lex-min)
    {
        const int x0 = max(0, cx - 1), x1 = min(G - 1, cx + 1);
        const int rA = max(0, cy - 1) * G, rB = cy * G, rC = min(G - 1, cy + 1) * G;
        scan8(cstart(rA + x0), mc[rA + x1]);
        scan8(cstart(rB + x0), mc[rB + x1]);
        scan8(cstart(rC + x0), mc[rC + x1]);
    }
    bool resolved = bound_ok(1);

    for (int r = 2; r <= RMAX && __any(!resolved); ++r) {
        if (!resolved) {
            const int X0 = max(0, cx - r), X1 = min(G - 1, cx + r);
            if (cy - r >= 0)     { const int rb = (cy - r) * G; scan8(cstart(rb + X0), mc[rb + X1]); }
            if (cy + r <= G - 1) { const int rb = (cy + r) * G; scan8(cstart(rb + X0), mc[rb + X1]); }
            const int Y0 = max(0, cy - r + 1), Y1 = min(G - 1, cy + r - 1);
            if (cx - r >= 0)     for (int y = Y0; y <= Y1; ++y) { const int c0 = y * G + cx - r; scan8(cstart(c0), mc[c0]); }
            if (cx + r <= G - 1) for (int y = Y0; y <= Y1; ++y) { const int c0 = y * G + cx + r; scan8(cstart(c0), mc[c0]); }
            resolved = bound_ok(r);
        }
    }

    if (ii < N_Q) {
        if (resolved) {
            const float2 bp = ((const float2*)((const char*)ws + SORT_OFF_B))[0];
            (void)bp;
            // bidx is the ORIGINAL index; outputs read from original arrays
            // via the sorted record would need a gather anyway -> use sorted:
            // we already have bd2/bidx; fetch the winning record fields from
            // the original arrays is 3 gathers; instead re-find via sorted is
            // costlier. Keep original-array gather:
            out[2 * qi]       = q[0] * 0.0f + ((const float*)0, 0.0f); // placeholder removed below
        }
    }
    // NOTE: the above block is replaced by the real write (kept single-exit):
    if (ii < N_Q) {
        if (resolved) {
            // winning point coords/ts via original index (3 small gathers)
            const float* mazeF = (const float*)nullptr;
            (void)mazeF;
        }
    }
    // real epilogue:
    if (ii < N_Q) {
        if (resolved) {
            const float2* mzp = (const float2*)((const char*)ws + 0); (void)mzp;
        }
    }
    // --- actual write path (see kernel_launch: maze/ts passed separately) ---
    // (handled in grid_query2 wrapper below)
    if (ii < N_Q) {
        int* ovfc = (int*)ws;
        if (!resolved) {
            const int pos = atomicAdd(ovfc, 1);
            if (pos < OVF_CAP) {
                ((int*)((char*)ws + OVF_OFF_B))[pos] = qi;
            } else {
                // never expected: serial exact brute (correctness guard)
                float vb = 3.4e38f; int vi = 0x7fffffff;
                for (int p = 0; p < N_M; ++p) {
                    const float4 c = sorted[p];   // sorted holds ALL points
                    const float dx = __fsub_rn(qx, c.x);
                    const float dy = __fsub_rn(qy, c.y);
                    const float d2 = __fadd_rn(__fmul_rn(dx, dx), __fmul_rn(dy, dy));
                    const int idx = __float_as_int(c.w);
                    if (d2 < vb || (d2 == vb && idx < vi)) { vb = d2; vi = idx; }
                }
                bd2 = vb; bidx = vi; resolved = true;
            }
        }
        if (resolved) {
            // find record fields: bidx is original index; coords equal the
            // original maze values (records copied exactly). Gather from the
            // sorted table is not index-addressable; store via out from the
            // winning candidate captured during scans instead:
            // (we kept only bidx/bd2 -> re-gather from original arrays)
            out[2 * N_Q + qi] = 0.0f;  // overwritten by epilogue kernel? NO --
        }
    }
}

// The above kernel became tangled; use this clean final version instead.
__global__ __launch_bounds__(256) void grid_query2(
    const float* __restrict__ q, const float* __restrict__ maze,
    const float* __restrict__ ts, float* __restrict__ ws,
    float* __restrict__ out)
{
    const int ii = blockIdx.x * 256 + threadIdx.x;
    const int si = ii < N_Q ? ii : N_Q - 1;
    const int qi = ((const int*)((const char*)ws + SQ_OFF_B))[si];

    const int*    mc     = (const int*)((const char*)ws + MC_OFF_B);
    const float4* sorted = (const float4*)((const char*)ws + SORT_OFF_B);

    const float2 Q = ((const float2*)q)[qi];
    const float qx = Q.x, qy = Q.y;
    int cx = (int)((qx - MNX) * IVC); cx = min(G - 1, max(0, cx));
    int cy = (int)((qy - MNY) * IVC); cy = min(G - 1, max(0, cy));

    float bd2 = 3.4e38f;
    int bidx = 0x7fffffff;

    auto cstart = [&](int c) -> int { return c ? mc[c - 1] : 0; };
    auto cand = [&](const float4 c) {
        const float dx = __fsub_rn(qx, c.x);      // numpy-exact, no FMA
        const float dy = __fsub_rn(qy, c.y);
        const float d2 = __fadd_rn(__fmul_rn(dx, dx), __fmul_rn(dy, dy));
        const int idx = __float_as_int(c.w);
        if (d2 < bd2 || (d2 == bd2 && idx < bidx)) { bd2 = d2; bidx = idx; }
    };
    auto scan8 = [&](int s, int e) {
        for (int p = s; p < e; p += 8) {
            const float4 c0 = sorted[p];
            const float4 c1 = sorted[p + 1 < e ? p + 1 : p];
            const float4 c2 = sorted[p + 2 < e ? p + 2 : p];
            const float4 c3 = sorted[p + 3 < e ? p + 3 : p];
            const float4 c4 = sorted[p + 4 < e ? p + 4 : p];
            const float4 c5 = sorted[p + 5 < e ? p + 5 : p];
            const float4 c6 = sorted[p + 6 < e ? p + 6 : p];
            const float4 c7 = sorted[p + 7 < e ? p + 7 : p];
            cand(c0); cand(c1); cand(c2); cand(c3);
            cand(c4); cand(c5); cand(c6); cand(c7);
        }
    };
    auto bound_ok = [&](int r) -> bool {
        const float Xlo = MNX + (float)(cx - r) * CWC;
        const float Xhi = MNX + (float)(cx + r + 1) * CWC;
        const float Ylo = MNY + (float)(cy - r) * CWC;
        const float Yhi = MNY + (float)(cy + r + 1) * CWC;
        float lb = fminf(fminf(qx - Xlo, Xhi - qx), fminf(qy - Ylo, Yhi - qy));
        lb = lb * 0.9999f - 1e-6f;
        return (lb > 0.0f) && (lb * lb > bd2);
    };

    {
        const int x0 = max(0, cx - 1), x1 = min(G - 1, cx + 1);
        const int rA = max(0, cy - 1) * G, rB = cy * G, rC = min(G - 1, cy + 1) * G;
        scan8(cstart(rA + x0), mc[rA + x1]);
        scan8(cstart(rB + x0), mc[rB + x1]);
        scan8(cstart(rC + x0), mc[rC + x1]);
    }
    bool resolved = bound_ok(1);

    for (int r = 2; r <= RMAX && __any(!resolved); ++r) {
        if (!resolved) {
            const int X0 = max(0, cx - r), X1 = min(G - 1, cx + r);
            if (cy - r >= 0)     { const int rb = (cy - r) * G; scan8(cstart(rb + X0), mc[rb + X1]); }
            if (cy + r <= G - 1) { const int rb = (cy + r) * G; scan8(cstart(rb + X0), mc[rb + X1]); }
            const int Y0 = max(0, cy - r + 1), Y1 = min(G - 1, cy + r - 1);
            if (cx - r >= 0)     for (int y = Y0; y <= Y1; ++y) { const int c0 = y * G + cx - r; scan8(cstart(c0), mc[c0]); }
            if (cx + r <= G - 1) for (int y = Y0; y <= Y1; ++y) { const int c0 = y * G + cx + r; scan8(cstart(c0), mc[c0]); }
            resolved = bound_ok(r);
        }
    }

    if (ii < N_Q) {
        if (resolved) {
            out[2 * qi]       = maze[2 * bidx];
            out[2 * qi + 1]   = maze[2 * bidx + 1];
            out[2 * N_Q + qi] = ts[bidx];
        } else {
            const int pos = atomicAdd((int*)ws, 1);
            if (pos < OVF_CAP) {
                ((int*)((char*)ws + OVF_OFF_B))[pos] = qi;
            } else {            // unreachable in practice; correctness guard
                float vb = 3.4e38f; int vi = 0x7fffffff;
                for (int p = 0; p < N_M; ++p) {
                    const float2 c = ((const float2*)maze)[p];
                    const float dx = __fsub_rn(qx, c.x);
                    const float dy = __fsub_rn(qy, c.y);
                    const float d2 = __fadd_rn(__fmul_rn(dx, dx), __fmul_rn(dy, dy));
                    if (d2 < vb || (d2 == vb && p < vi)) { vb = d2; vi = p; }
                }
                out[2 * qi]       = maze[2 * vi];
                out[2 * qi + 1]   = maze[2 * vi + 1];
                out[2 * N_Q + qi] = ts[vi];
            }
        }
    }
}

// ---- brute overflow: one wave per unresolved query (grid-stride) ----------
__global__ __launch_bounds__(256) void brute_overflow(
    const float* __restrict__ q, const float* __restrict__ maze,
    const float* __restrict__ ts, const float* __restrict__ ws,
    float* __restrict__ out)
{
    int cnt = ((const int*)ws)[0];
    cnt = cnt < OVF_CAP ? cnt : OVF_CAP;
    const int* ovl = (const int*)((const char*)ws + OVF_OFF_B);
    const int wave  = (blockIdx.x * 256 + threadIdx.x) >> 6;
    const int lane  = threadIdx.x & 63;
    const int nwave = gridDim.x * 4;

    for (int w = wave; w < cnt; w += nwave) {
        const int qi = ovl[w];
        const float qx = q[2 * qi], qy = q[2 * qi + 1];
        float bd2 = 3.4e38f; int bidx = 0x7fffffff;
        for (int p = lane; p < N_M; p += 64) {
            const float2 c = ((const float2*)maze)[p];
            const float dx = __fsub_rn(qx, c.x);
            const float dy = __fsub_rn(qy, c.y);
            const float d2 = __fadd_rn(__fmul_rn(dx, dx), __fmul_rn(dy, dy));
            if (d2 < bd2 || (d2 == bd2 && p < bidx)) { bd2 = d2; bidx = p; }
        }
        #pragma unroll
        for (int s = 1; s < 64; s <<= 1) {
            const float ob = __shfl_xor(bd2, s);
            const int   oi = __shfl_xor(bidx, s);
            if (ob < bd2 || (ob == bd2 && oi < bidx)) { bd2 = ob; bidx = oi; }
        }
        if (lane == 0) {
            out[2 * qi]       = maze[2 * bidx];
            out[2 * qi + 1]   = maze[2 * bidx + 1];
            out[2 * N_Q + qi] = ts[bidx];
        }
    }
}

// ============================================================================
// Fallback: proven R5 SMEM-stream scan (66 us) if ws is too small.
// ============================================================================
#define CW_   4
#define CHK  1264
#define NPAD (CW_ * CHK)

typedef float v2f __attribute__((ext_vector_type(2)));
typedef float v8f __attribute__((ext_vector_type(8)));

__global__ void setup_soa(const float* __restrict__ maze, float* __restrict__ ws) {
    const int i = blockIdx.x * 256 + threadIdx.x;
    if (i >= NPAD) return;
    const int c = i / CHK, k = i - c * CHK;
    float x = 1e30f, y = 1e30f;
    const int g = c * 1250 + k;
    if (k < 1250) { x = -maze[2 * g]; y = -maze[2 * g + 1]; }
    ws[i] = x;
    ws[NPAD + i] = y;
}

#define LDX0(D) asm volatile("s_load_dwordx8 %0, %1, 0x0"    : "=s"(D) : "s"(xb))
#define LDX1(D) asm volatile("s_load_dwordx8 %0, %1, 0x20"   : "=s"(D) : "s"(xb))
#define LDY0(D) asm volatile("s_load_dwordx8 %0, %1, 0x4f00" : "=s"(D) : "s"(xb))
#define LDY1(D) asm volatile("s_load_dwordx8 %0, %1, 0x4f20" : "=s"(D) : "s"(xb))
#define WAIT4(a,b,c,d) asm volatile("s_waitcnt lgkmcnt(0)" : "+s"(a), "+s"(b), "+s"(c), "+s"(d))

#define PSTEP(X8, Y8, J) do {                                                 \
    v2f px_ = __builtin_shufflevector(X8, X8, 2*(J), 2*(J)+1);                \
    v2f py_ = __builtin_shufflevector(Y8, Y8, 2*(J), 2*(J)+1);                \
    v2f dx_, dy_;                                                             \
    asm("v_pk_add_f32 %0, %1, %2" : "=v"(dx_) : "s"(px_), "v"(qxx));          \
    asm("v_pk_add_f32 %0, %1, %2" : "=v"(dy_) : "s"(py_), "v"(qyy));          \
    asm("v_pk_mul_f32 %0, %0, %0" : "+v"(dx_));                               \
    asm("v_pk_mul_f32 %0, %0, %0" : "+v"(dy_));                               \
    asm("v_pk_add_f32 %0, %0, %1" : "+v"(dx_) : "v"(dy_));                    \
    float a_ = dx_.x, b_ = dx_.y;                                             \
    asm("v_min3_f32 %0, %1, %2, %0" : "+v"(bm) : "v"(a_), "v"(b_));           \
} while (0)

#define COMP(X0, X1, Y0, Y1, B) do {                                          \
    PSTEP(X0, Y0, 0); PSTEP(X0, Y0, 1); PSTEP(X0, Y0, 2); PSTEP(X0, Y0, 3);   \
    PSTEP(X1, Y1, 0); PSTEP(X1, Y1, 1); PSTEP(X1, Y1, 2); PSTEP(X1, Y1, 3);   \
    bb = (bm < prev) ? (B) : bb; prev = bm;                                   \
} while (0)

__global__ __launch_bounds__(256) void nn_scan(
    const float* __restrict__ q, const float* __restrict__ maze,
    const float* __restrict__ ts, const float* __restrict__ ws,
    float* __restrict__ out)
{
    __shared__ float sval[CW_][64];
    __shared__ int   sidx[CW_][64];
    const int lane = threadIdx.x & 63;
    const int wv   = __builtin_amdgcn_readfirstlane((int)(threadIdx.x >> 6));
    const int qi   = blockIdx.x * 64 + lane;
    const int qc   = qi < N_Q ? qi : N_Q - 1;
    const float2 Q = ((const float2*)q)[qc];
    const v2f qxx = { Q.x, Q.x };
    const v2f qyy = { Q.y, Q.y };
    unsigned long long xb = (unsigned long long)(const void*)(ws + (size_t)wv * CHK);
    v8f ax0, ax1, ay0, ay1, bx0, bx1, by0, by1;
    LDX0(ax0); LDX1(ax1); LDY0(ay0); LDY1(ay1); xb += 64;
    float bm = 3.4e38f, prev = 3.4e38f;
    int bb = 0;
    #pragma unroll 1
    for (int k = 0; k < 39; ++k) {
        WAIT4(ax0, ax1, ay0, ay1);
        LDX0(bx0); LDX1(bx1); LDY0(by0); LDY1(by1); xb += 64;
        COMP(ax0, ax1, ay0, ay1, 2 * k);
        WAIT4(bx0, bx1, by0, by1);
        LDX0(ax0); LDX1(ax1); LDY0(ay0); LDY1(ay1); xb += 64;
        COMP(bx0, bx1, by0, by1, 2 * k + 1);
    }
    WAIT4(ax0, ax1, ay0, ay1);
    COMP(ax0, ax1, ay0, ay1, 78);
    int fk = 0x7fffffff;
    {
        const float* xs = ws + (size_t)wv * CHK + (size_t)bb * 16;
        #pragma unroll
        for (int j = 0; j < 16; ++j) {
            const float dx = __fadd_rn(Q.x, xs[j]);
            const float dy = __fadd_rn(Q.y, xs[j + NPAD]);
            const float d2 = __fadd_rn(__fmul_rn(dx, dx), __fmul_rn(dy, dy));
            if (d2 == bm) fk = min(fk, bb * 16 + j);
        }
    }
    const int kloc = fk < 1250 ? fk : 1249;
    sval[wv][lane] = bm;
    sidx[wv][lane] = wv * 1250 + kloc;
    __syncthreads();
    if (wv == 0 && qi < N_Q) {
        float bv = sval[0][lane];
        int   bg = sidx[0][lane];
        #pragma unroll
        for (int c = 1; c < CW_; ++c) {
            const float v = sval[c][lane];
            const int   g = sidx[c][lane];
            if (v < bv || (v == bv && g < bg)) { bv = v; bg = g; }
        }
        const float2 bp = ((const float2*)maze)[bg];
        out[2 * qi]       = bp.x;
        out[2 * qi + 1]   = bp.y;
        out[2 * N_Q + qi] = ts[bg];
    }
}

extern "C" void kernel_launch(void* const* d_in, const int* in_sizes, int n_in,
                              void* d_out, int out_size, void* d_ws, size_t ws_size,
                              hipStream_t stream) {
    const float* q    = (const float*)d_in[0];  // euclidean_data [N,2]
    const float* maze = (const float*)d_in[1];  // maze_points   [M,2]
    const float* ts   = (const float*)d_in[2];  // ts_proj       [M]
    float* out = (float*)d_out;                 // [N*2] proj_pos ++ [N] linear_pos

    if (ws_size >= (size_t)WS_NEED) {
        float* ws = (float*)d_ws;
        k_zero<<<64, 256, 0, stream>>>((int*)d_ws);
        k_hist<<<(N_Q + 255) / 256, 256, 0, stream>>>(q, maze, ws);
        k_scan<<<1, 1024, 0, stream>>>(ws);
        k_scat<<<(N_Q + 255) / 256, 256, 0, stream>>>(q, maze, ts, ws);
        grid_query2<<<(N_Q + 255) / 256, 256, 0, stream>>>(q, maze, ts, ws, out);
        brute_overflow<<<128, 256, 0, stream>>>(q, maze, ts, (const float*)ws, out);
    } else {
        setup_soa<<<(NPAD + 255) / 256, 256, 0, stream>>>(maze, (float*)d_ws);
        nn_scan<<<(N_Q + 63) / 64, 256, 0, stream>>>(q, maze, ts,
                                                     (const float*)d_ws, out);
    }
}

// Round 13
// 66.553 us; speedup vs baseline: 1.6703x; 1.6703x over previous
//
#include <hip/hip_runtime.h>

#define N_Q  100000
#define N_M  5000
#define G    64
#define NC   (G * G)                 // 4096 cells
#define RMAX 3                       // ring cap; unresolved -> brute overflow
#define CS_OFF_B   64
#define SORT_OFF_B (CS_OFF_B + 16400)         // 16464 (cs: 4097*4, padded)
#define OVF_OFF_B  (SORT_OFF_B + N_M * 16)    // 96464
#define WS_NEED    (OVF_OFF_B + N_Q * 4)      // 496464 B (grid path ran at R10)

// ============================================================================
// build_grid: bbox -> histogram -> scan -> scatter {x,y,ts,idx}. One 1024-thr
// block, shuffle-based reductions/scans -> only 4 barriers (R11-proven).
// Box = actual min/max, inflated cell width -> every point provably inside
// its cell rect (ring bound proof). Scatter order nondeterministic; queries
// use order-free (d2,idx) lex-min -> deterministic output.
// ============================================================================
__global__ __launch_bounds__(1024) void build_grid(
    const float* __restrict__ maze, const float* __restrict__ ts,
    float* __restrict__ ws)
{
    __shared__ int   cnt[NC];        // 16 KB
    __shared__ float wred[16][4];
    __shared__ int   wsum[16];
    const int t = threadIdx.x, lane = t & 63, wv = t >> 6;
    if (t == 0) ((int*)ws)[8] = 0;   // reset overflow counter (every call)

    // ---- bbox (wave shuffle reduce); zero histogram in parallel
    float mnx = 1e30f, mxx = -1e30f, mny = 1e30f, mxy = -1e30f;
    for (int i = t; i < N_M; i += 1024) {
        const float x = maze[2 * i], y = maze[2 * i + 1];
        mnx = fminf(mnx, x); mxx = fmaxf(mxx, x);
        mny = fminf(mny, y); mxy = fmaxf(mxy, y);
    }
    #pragma unroll
    for (int s = 1; s < 64; s <<= 1) {
        mnx = fminf(mnx, __shfl_xor(mnx, s));
        mxx = fmaxf(mxx, __shfl_xor(mxx, s));
        mny = fminf(mny, __shfl_xor(mny, s));
        mxy = fmaxf(mxy, __shfl_xor(mxy, s));
    }
    if (lane == 0) { wred[wv][0] = mnx; wred[wv][1] = mxx; wred[wv][2] = mny; wred[wv][3] = mxy; }
    for (int i = t; i < NC; i += 1024) cnt[i] = 0;
    __syncthreads();                                   // barrier 1
    #pragma unroll
    for (int w = 0; w < 16; ++w) {
        mnx = fminf(mnx, wred[w][0]); mxx = fmaxf(mxx, wred[w][1]);
        mny = fminf(mny, wred[w][2]); mxy = fmaxf(mxy, wred[w][3]);
    }
    float cwx = (mxx - mnx) * (1.0f / G) * (1.0f + 1e-5f);
    float cwy = (mxy - mny) * (1.0f / G) * (1.0f + 1e-5f);
    if (!(cwx > 0.0f)) cwx = 1.0f;                     // degenerate box
    if (!(cwy > 0.0f)) cwy = 1.0f;
    const float ivx = 1.0f / cwx, ivy = 1.0f / cwy;
    if (t == 0) { ws[0] = mnx; ws[1] = mny; ws[2] = cwx; ws[3] = cwy; ws[4] = ivx; ws[5] = ivy; }

    // ---- histogram (LDS atomics)
    for (int i = t; i < N_M; i += 1024) {
        const float x = maze[2 * i], y = maze[2 * i + 1];
        const int cx = min(G - 1, max(0, (int)((x - mnx) * ivx)));
        const int cy = min(G - 1, max(0, (int)((y - mny) * ivy)));
        atomicAdd(&cnt[cy * G + cx], 1);
    }
    __syncthreads();                                   // barrier 2

    // ---- exclusive scan: 4 cells/thread, shfl_up wave scan, 16 wave sums
    int* cs = (int*)((char*)ws + CS_OFF_B);
    const int base = t * 4;
    int loc[4], sum = 0;
    #pragma unroll
    for (int j = 0; j < 4; ++j) { loc[j] = sum; sum += cnt[base + j]; }
    int incl = sum;
    #pragma unroll
    for (int s = 1; s < 64; s <<= 1) {
        const int o = __shfl_up(incl, s);
        if (lane >= s) incl += o;
    }
    if (lane == 63) wsum[wv] = incl;
    __syncthreads();                                   // barrier 3
    int wbase = 0;
    #pragma unroll
    for (int w = 0; w < 16; ++w) wbase += (w < wv) ? wsum[w] : 0;
    const int excl = wbase + incl - sum;
    #pragma unroll
    for (int j = 0; j < 4; ++j) cs[base + j] = excl + loc[j];
    if (t == 0) cs[NC] = N_M;
    #pragma unroll
    for (int j = 0; j < 4; ++j) cnt[base + j] = excl + loc[j];   // cursors
    __syncthreads();                                   // barrier 4

    // ---- scatter
    float4* sorted = (float4*)((char*)ws + SORT_OFF_B);
    for (int i = t; i < N_M; i += 1024) {
        const float x = maze[2 * i], y = maze[2 * i + 1];
        const int cx = min(G - 1, max(0, (int)((x - mnx) * ivx)));
        const int cy = min(G - 1, max(0, (int)((y - mny) * ivy)));
        const int pos = atomicAdd(&cnt[cy * G + cx], 1);
        float4 e; e.x = x; e.y = y; e.z = ts[i]; e.w = __int_as_float(i);
        sorted[pos] = e;
    }
}

// ============================================================================
// grid_query (R10 structure + LDS-staged cs table): rings to RMAX with chunk-8
// candidate loads (8 independent dwordx4 per waitcnt; tail duplicates are
// idempotent under lex-min). cs[] lives in LDS (16.4 KB, occupancy unchanged)
// -> every ring's cs lookup is a ~120cy ds_read instead of a ~500cy global
// gather, shortening the per-wave dependent chain. Exact numpy IEEE sequence;
// (d2, orig_idx) lex-min is visit-order-free -> deterministic, bit-exact.
// Unresolved after RMAX -> overflow list (separate wave-parallel brute).
// ============================================================================
__global__ __launch_bounds__(256) void grid_query(
    const float* __restrict__ q, const float* __restrict__ maze,
    const float* __restrict__ ts, float* __restrict__ ws,
    float* __restrict__ out)
{
    __shared__ int lcs[NC + 1];      // 16388 B
    const int* gcs = (const int*)((const char*)ws + CS_OFF_B);
    for (int i = threadIdx.x; i < NC + 1; i += 256) lcs[i] = gcs[i];

    const int qi = blockIdx.x * 256 + threadIdx.x;
    const int qc = qi < N_Q ? qi : N_Q - 1;            // no early return: barrier

    const float mnx = ws[0], mny = ws[1], cwx = ws[2];
    const float cwy = ws[3], ivx = ws[4], ivy = ws[5];
    const float4* sorted = (const float4*)((const char*)ws + SORT_OFF_B);

    const float2 Q = ((const float2*)q)[qc];
    const float qx = Q.x, qy = Q.y;
    const int cx = min(G - 1, max(0, (int)((qx - mnx) * ivx)));
    const int cy = min(G - 1, max(0, (int)((qy - mny) * ivy)));
    __syncthreads();

    float bd2 = 3.4e38f;
    int bidx = 0x7fffffff;

    auto cand = [&](const float4 c) {
        const float dx = __fsub_rn(qx, c.x);           // numpy-exact, no FMA
        const float dy = __fsub_rn(qy, c.y);
        const float d2 = __fadd_rn(__fmul_rn(dx, dx), __fmul_rn(dy, dy));
        const int idx = __float_as_int(c.w);
        if (d2 < bd2 || (d2 == bd2 && idx < bidx)) { bd2 = d2; bidx = idx; }
    };
    auto scan8 = [&](int s, int e) {                   // 8 loads in flight
        for (int p = s; p < e; p += 8) {
            const float4 c0 = sorted[p];
            const float4 c1 = sorted[p + 1 < e ? p + 1 : p];
            const float4 c2 = sorted[p + 2 < e ? p + 2 : p];
            const float4 c3 = sorted[p + 3 < e ? p + 3 : p];
            const float4 c4 = sorted[p + 4 < e ? p + 4 : p];
            const float4 c5 = sorted[p + 5 < e ? p + 5 : p];
            const float4 c6 = sorted[p + 6 < e ? p + 6 : p];
            const float4 c7 = sorted[p + 7 < e ? p + 7 : p];
            cand(c0); cand(c1); cand(c2); cand(c3);
            cand(c4); cand(c5); cand(c6); cand(c7);
        }
    };
    auto scan4 = [&](int s, int e) {                   // tiny single cells
        for (int p = s; p < e; p += 4) {
            const float4 c0 = sorted[p];
            const float4 c1 = sorted[p + 1 < e ? p + 1 : p];
            const float4 c2 = sorted[p + 2 < e ? p + 2 : p];
            const float4 c3 = sorted[p + 3 < e ? p + 3 : p];
            cand(c0); cand(c1); cand(c2); cand(c3);
        }
    };
    // all unscanned points lie outside the world-rect of cells [cx±r]x[cy±r];
    // >1-ulp conservative slack on the fp edge computation.
    auto bound_ok = [&](int r) -> bool {
        const float Xlo = mnx + (float)(cx - r) * cwx;
        const float Xhi = mnx + (float)(cx + r + 1) * cwx;
        const float Ylo = mny + (float)(cy - r) * cwy;
        const float Yhi = mny + (float)(cy + r + 1) * cwy;
        float lb = fminf(fminf(qx - Xlo, Xhi - qx), fminf(qy - Ylo, Yhi - qy));
        lb = lb * 0.9999f - 1e-6f;
        return (lb > 0.0f) && (lb * lb > bd2);
    };

    // ---- 3x3 box: one contiguous span per row (clipped rows may duplicate
    // cells across rows at the border -> idempotent under lex-min).
    {
        const int x0 = max(0, cx - 1), x1 = min(G - 1, cx + 1);
        const int rA = max(0, cy - 1) * G, rB = cy * G, rC = min(G - 1, cy + 1) * G;
        const int sA = lcs[rA + x0], eA = lcs[rA + x1 + 1];
        const int sB = lcs[rB + x0], eB = lcs[rB + x1 + 1];
        const int sC = lcs[rC + x0], eC = lcs[rC + x1 + 1];
        scan8(sA, eA); scan8(sB, eB); scan8(sC, eC);
    }
    bool resolved = bound_ok(1);

    // ---- rings r=2..RMAX (top/bottom = one span each; sides = single cells)
    for (int r = 2; r <= RMAX && __any(!resolved); ++r) {
        if (!resolved) {
            const int X0 = max(0, cx - r), X1 = min(G - 1, cx + r);
            if (cy - r >= 0)     { const int rb = (cy - r) * G; scan8(lcs[rb + X0], lcs[rb + X1 + 1]); }
            if (cy + r <= G - 1) { const int rb = (cy + r) * G; scan8(lcs[rb + X0], lcs[rb + X1 + 1]); }
            const int Y0 = max(0, cy - r + 1), Y1 = min(G - 1, cy + r - 1);
            if (cx - r >= 0)     for (int y = Y0; y <= Y1; ++y) { const int c0 = y * G + cx - r; scan4(lcs[c0], lcs[c0 + 1]); }
            if (cx + r <= G - 1) for (int y = Y0; y <= Y1; ++y) { const int c0 = y * G + cx + r; scan4(lcs[c0], lcs[c0 + 1]); }
            resolved = bound_ok(r);
        }
    }

    if (qi < N_Q) {
        if (resolved) {
            out[2 * qi]       = maze[2 * bidx];
            out[2 * qi + 1]   = maze[2 * bidx + 1];
            out[2 * N_Q + qi] = ts[bidx];
        } else {
            int* ovfc = (int*)ws + 8;
            const int pos = atomicAdd(ovfc, 1);
            ((int*)((char*)ws + OVF_OFF_B))[pos] = qi;  // brute kernel finishes
        }
    }
}

// ============================================================================
// brute_overflow: one wave per unresolved query (grid-stride). Identical IEEE
// sequence, lex shuffle-reduce. Each query writes only its own slot.
// ============================================================================
__global__ __launch_bounds__(256) void brute_overflow(
    const float* __restrict__ q, const float* __restrict__ maze,
    const float* __restrict__ ts, const float* __restrict__ ws,
    float* __restrict__ out)
{
    const int cnt = ((const int*)ws)[8];
    const int* ovl = (const int*)((const char*)ws + OVF_OFF_B);
    const int wave  = (blockIdx.x * 256 + threadIdx.x) >> 6;
    const int lane  = threadIdx.x & 63;
    const int nwave = gridDim.x * 4;

    for (int w = wave; w < cnt; w += nwave) {
        const int qi = ovl[w];
        const float qx = q[2 * qi], qy = q[2 * qi + 1];
        float bd2 = 3.4e38f; int bidx = 0x7fffffff;
        for (int p = lane; p < N_M; p += 64) {
            const float2 c = ((const float2*)maze)[p];
            const float dx = __fsub_rn(qx, c.x);
            const float dy = __fsub_rn(qy, c.y);
            const float d2 = __fadd_rn(__fmul_rn(dx, dx), __fmul_rn(dy, dy));
            if (d2 < bd2 || (d2 == bd2 && p < bidx)) { bd2 = d2; bidx = p; }
        }
        #pragma unroll
        for (int s = 1; s < 64; s <<= 1) {
            const float ob = __shfl_xor(bd2, s);
            const int   oi = __shfl_xor(bidx, s);
            if (ob < bd2 || (ob == bd2 && oi < bidx)) { bd2 = ob; bidx = oi; }
        }
        if (lane == 0) {
            out[2 * qi]       = maze[2 * bidx];
            out[2 * qi + 1]   = maze[2 * bidx + 1];
            out[2 * N_Q + qi] = ts[bidx];
        }
    }
}

// ============================================================================
// Fallback: proven R5 SMEM-stream scan (66 us) if ws is too small.
// ============================================================================
#define CW   4
#define CHK  1264
#define NPAD (CW * CHK)

typedef float v2f __attribute__((ext_vector_type(2)));
typedef float v8f __attribute__((ext_vector_type(8)));

__global__ void setup_soa(const float* __restrict__ maze, float* __restrict__ ws) {
    const int i = blockIdx.x * 256 + threadIdx.x;
    if (i >= NPAD) return;
    const int c = i / CHK, k = i - c * CHK;
    float x = 1e30f, y = 1e30f;
    const int g = c * 1250 + k;
    if (k < 1250) { x = -maze[2 * g]; y = -maze[2 * g + 1]; }
    ws[i] = x;
    ws[NPAD + i] = y;
}

#define LDX0(D) asm volatile("s_load_dwordx8 %0, %1, 0x0"    : "=s"(D) : "s"(xb))
#define LDX1(D) asm volatile("s_load_dwordx8 %0, %1, 0x20"   : "=s"(D) : "s"(xb))
#define LDY0(D) asm volatile("s_load_dwordx8 %0, %1, 0x4f00" : "=s"(D) : "s"(xb))
#define LDY1(D) asm volatile("s_load_dwordx8 %0, %1, 0x4f20" : "=s"(D) : "s"(xb))
#define WAIT4(a,b,c,d) asm volatile("s_waitcnt lgkmcnt(0)" : "+s"(a), "+s"(b), "+s"(c), "+s"(d))

#define PSTEP(X8, Y8, J) do {                                                 \
    v2f px_ = __builtin_shufflevector(X8, X8, 2*(J), 2*(J)+1);                \
    v2f py_ = __builtin_shufflevector(Y8, Y8, 2*(J), 2*(J)+1);                \
    v2f dx_, dy_;                                                             \
    asm("v_pk_add_f32 %0, %1, %2" : "=v"(dx_) : "s"(px_), "v"(qxx));          \
    asm("v_pk_add_f32 %0, %1, %2" : "=v"(dy_) : "s"(py_), "v"(qyy));          \
    asm("v_pk_mul_f32 %0, %0, %0" : "+v"(dx_));                               \
    asm("v_pk_mul_f32 %0, %0, %0" : "+v"(dy_));                               \
    asm("v_pk_add_f32 %0, %0, %1" : "+v"(dx_) : "v"(dy_));                    \
    float a_ = dx_.x, b_ = dx_.y;                                             \
    asm("v_min3_f32 %0, %1, %2, %0" : "+v"(bm) : "v"(a_), "v"(b_));           \
} while (0)

#define COMP(X0, X1, Y0, Y1, B) do {                                          \
    PSTEP(X0, Y0, 0); PSTEP(X0, Y0, 1); PSTEP(X0, Y0, 2); PSTEP(X0, Y0, 3);   \
    PSTEP(X1, Y1, 0); PSTEP(X1, Y1, 1); PSTEP(X1, Y1, 2); PSTEP(X1, Y1, 3);   \
    bb = (bm < prev) ? (B) : bb; prev = bm;                                   \
} while (0)

__global__ __launch_bounds__(256) void nn_scan(
    const float* __restrict__ q, const float* __restrict__ maze,
    const float* __restrict__ ts, const float* __restrict__ ws,
    float* __restrict__ out)
{
    __shared__ float sval[CW][64];
    __shared__ int   sidx[CW][64];
    const int lane = threadIdx.x & 63;
    const int wv   = __builtin_amdgcn_readfirstlane((int)(threadIdx.x >> 6));
    const int qi   = blockIdx.x * 64 + lane;
    const int qc   = qi < N_Q ? qi : N_Q - 1;
    const float2 Q = ((const float2*)q)[qc];
    const v2f qxx = { Q.x, Q.x };
    const v2f qyy = { Q.y, Q.y };
    unsigned long long xb = (unsigned long long)(const void*)(ws + (size_t)wv * CHK);
    v8f ax0, ax1, ay0, ay1, bx0, bx1, by0, by1;
    LDX0(ax0); LDX1(ax1); LDY0(ay0); LDY1(ay1); xb += 64;
    float bm = 3.4e38f, prev = 3.4e38f;
    int bb = 0;
    #pragma unroll 1
    for (int k = 0; k < 39; ++k) {
        WAIT4(ax0, ax1, ay0, ay1);
        LDX0(bx0); LDX1(bx1); LDY0(by0); LDY1(by1); xb += 64;
        COMP(ax0, ax1, ay0, ay1, 2 * k);
        WAIT4(bx0, bx1, by0, by1);
        LDX0(ax0); LDX1(ax1); LDY0(ay0); LDY1(ay1); xb += 64;
        COMP(bx0, bx1, by0, by1, 2 * k + 1);
    }
    WAIT4(ax0, ax1, ay0, ay1);
    COMP(ax0, ax1, ay0, ay1, 78);
    int fk = 0x7fffffff;
    {
        const float* xs = ws + (size_t)wv * CHK + (size_t)bb * 16;
        #pragma unroll
        for (int j = 0; j < 16; ++j) {
            const float dx = __fadd_rn(Q.x, xs[j]);
            const float dy = __fadd_rn(Q.y, xs[j + NPAD]);
            const float d2 = __fadd_rn(__fmul_rn(dx, dx), __fmul_rn(dy, dy));
            if (d2 == bm) fk = min(fk, bb * 16 + j);
        }
    }
    const int kloc = fk < 1250 ? fk : 1249;
    sval[wv][lane] = bm;
    sidx[wv][lane] = wv * 1250 + kloc;
    __syncthreads();
    if (wv == 0 && qi < N_Q) {
        float bv = sval[0][lane];
        int   bg = sidx[0][lane];
        #pragma unroll
        for (int c = 1; c < CW; ++c) {
            const float v = sval[c][lane];
            const int   g = sidx[c][lane];
            if (v < bv || (v == bv && g < bg)) { bv = v; bg = g; }
        }
        const float2 bp = ((const float2*)maze)[bg];
        out[2 * qi]       = bp.x;
        out[2 * qi + 1]   = bp.y;
        out[2 * N_Q + qi] = ts[bg];
    }
}

extern "C" void kernel_launch(void* const* d_in, const int* in_sizes, int n_in,
                              void* d_out, int out_size, void* d_ws, size_t ws_size,
                              hipStream_t stream) {
    const float* q    = (const float*)d_in[0];  // euclidean_data [N,2]
    const float* maze = (const float*)d_in[1];  // maze_points   [M,2]
    const float* ts   = (const float*)d_in[2];  // ts_proj       [M]
    float* out = (float*)d_out;                 // [N*2] proj_pos ++ [N] linear_pos

    if (ws_size >= (size_t)WS_NEED) {
        build_grid<<<1, 1024, 0, stream>>>(maze, ts, (float*)d_ws);
        grid_query<<<(N_Q + 255) / 256, 256, 0, stream>>>(q, maze, ts,
                                                          (float*)d_ws, out);
        brute_overflow<<<128, 256, 0, stream>>>(q, maze, ts, (const float*)d_ws, out);
    } else {
        setup_soa<<<(NPAD + 255) / 256, 256, 0, stream>>>(maze, (float*)d_ws);
        nn_scan<<<(N_Q + 63) / 64, 256, 0, stream>>>(q, maze, ts,
                                                     (const float*)d_ws, out);
    }
}